// Round 2
// baseline (232.582 us; speedup 1.0000x reference)
//
#include <hip/hip_runtime.h>
#include <hip/hip_bf16.h>

// Grapher block (ViG-style): RepCPE(dw7x7+res) -> fc1+BN -> MRConv4d(K=2) -> gc(2C->C)+BN+GELU -> fc2+BN
// B=32, C=192, H=W=56. Device tensors are FLOAT32 (round-1 NaN = f32 read as bf16).
//
// Pipeline (fp32 accumulate, bf16 intermediate storage for MFMA):
//   fold:   BN-fold weights -> W1f[192][192], Wgf[192][384], W2f[192][192] (bf16), biases fp32
//   dwconv: per-(b,c) plane f32 in LDS 62x64, 4x1 register strips -> y0 bf16 [b][c][hw]
//   gemm1:  y1[p][o] = y0 * W1f   (MFMA 16x16x32, D[p][o])  -> y1 bf16 pixel-major (in d_out)
//   xj:     max-relative over 4 cyclic rolls -> xjb bf16 pixel-major
//   gemm2:  y2 = GELU(BN(gc([y1,xj])))  (K=384, D[p][o])    -> y2 bf16 pixel-major
//   gemm3:  out = BN(fc2(y2))  (operands swapped: D[o][p])  -> d_out FLOAT32 channel-major

#define CC   192
#define HW   3136
#define NB   32

using short8 = __attribute__((ext_vector_type(8))) short;
using f32x4  = __attribute__((ext_vector_type(4))) float;

__device__ __forceinline__ float bf2f(short s) {
  union { unsigned u; float f; } x; x.u = ((unsigned)(unsigned short)s) << 16; return x.f;
}
__device__ __forceinline__ short f2bf(float f) {
  __hip_bfloat16 h = __float2bfloat16(f);
  return *reinterpret_cast<short*>(&h);
}
__device__ __forceinline__ float geluf(float v) {
  return 0.5f * v * (1.0f + erff(v * 0.70710678118654752f));
}

// ---------------- fold: BN into weights/bias (f32 params -> bf16 W, f32 bias) ----------------
__global__ void __launch_bounds__(256) fold_kernel(
    const float* __restrict__ fc1_w, const float* __restrict__ fc1_b,
    const float* __restrict__ bn1_g, const float* __restrict__ bn1_b,
    const float* __restrict__ bn1_m, const float* __restrict__ bn1_v,
    const float* __restrict__ gc_w,  const float* __restrict__ gc_b,
    const float* __restrict__ bng_g, const float* __restrict__ bng_b,
    const float* __restrict__ bng_m, const float* __restrict__ bng_v,
    const float* __restrict__ fc2_w, const float* __restrict__ fc2_b,
    const float* __restrict__ bn2_g, const float* __restrict__ bn2_b,
    const float* __restrict__ bn2_m, const float* __restrict__ bn2_v,
    __hip_bfloat16* __restrict__ W1f, __hip_bfloat16* __restrict__ Wgf, __hip_bfloat16* __restrict__ W2f,
    float* __restrict__ b1f, float* __restrict__ bgf, float* __restrict__ b2f) {
  int gt = blockIdx.x * 256 + threadIdx.x;
  if (gt < 3 * CC) {
    int which = gt / CC, o = gt - which * CC;
    const float *G, *Bt, *M, *V, *Bi; float* dst;
    if (which == 0)      { G = bn1_g; Bt = bn1_b; M = bn1_m; V = bn1_v; Bi = fc1_b; dst = b1f; }
    else if (which == 1) { G = bng_g; Bt = bng_b; M = bng_m; V = bng_v; Bi = gc_b;  dst = bgf; }
    else                 { G = bn2_g; Bt = bn2_b; M = bn2_m; V = bn2_v; Bi = fc2_b; dst = b2f; }
    float inv = G[o] * rsqrtf(V[o] + 1e-5f);
    dst[o] = Bi[o] * inv + Bt[o] - M[o] * inv;
  }
  int i = gt;
  if (i < CC * CC) {
    int o = i / CC;
    float inv = bn1_g[o] * rsqrtf(bn1_v[o] + 1e-5f);
    W1f[i] = __float2bfloat16(fc1_w[i] * inv);
  } else if (i < CC * CC + CC * 2 * CC) {
    int j = i - CC * CC; int o = j / (2 * CC);
    float inv = bng_g[o] * rsqrtf(bng_v[o] + 1e-5f);
    Wgf[j] = __float2bfloat16(gc_w[j] * inv);
  } else if (i < CC * CC * 4) {
    int j = i - CC * CC * 3; int o = j / CC;
    float inv = bn2_g[o] * rsqrtf(bn2_v[o] + 1e-5f);
    W2f[j] = __float2bfloat16(fc2_w[j] * inv);
  }
}

// ---------------- dw 7x7 + bias + residual (f32 in -> bf16 out) ----------------
__global__ void __launch_bounds__(256) dwconv_kernel(
    const float* __restrict__ x, const float* __restrict__ cw,
    const float* __restrict__ cb, __hip_bfloat16* __restrict__ y0) {
  __shared__ float pl[62 * 64];
  __shared__ float wt[49];
  const int t = threadIdx.x;
  const int plane = blockIdx.x;           // b*192 + c
  const int c = plane % CC;
  const float* xp = x + (size_t)plane * HW;
  for (int i = t; i < 62 * 64; i += 256) pl[i] = 0.0f;
  __syncthreads();
  for (int ch = t; ch < 784; ch += 256) {       // 56 rows x 14 chunks of 4
    int h = ch / 14, wb = (ch - h * 14) * 4;
    float4 v = *(const float4*)(xp + h * 56 + wb);
    float* d = &pl[(h + 3) * 64 + wb + 3];
    d[0] = v.x; d[1] = v.y; d[2] = v.z; d[3] = v.w;
  }
  if (t < 49) wt[t] = cw[c * 49 + t];
  __syncthreads();
  const float bias = cb[c];
  short* yp = (short*)y0 + (size_t)plane * HW;
  for (int s = t; s < 784; s += 256) {          // 4x1 vertical strips
    int hi = s / 56, wc = s - hi * 56;
    int h0 = hi * 4;
    float a0 = 0, a1 = 0, a2 = 0, a3 = 0;
#pragma unroll
    for (int kw = 0; kw < 7; ++kw) {
      float v[10];
#pragma unroll
      for (int rr = 0; rr < 10; ++rr) v[rr] = pl[(h0 + rr) * 64 + wc + kw];
#pragma unroll
      for (int kh = 0; kh < 7; ++kh) {
        float wv = wt[kh * 7 + kw];
        a0 = fmaf(wv, v[kh], a0);
        a1 = fmaf(wv, v[kh + 1], a1);
        a2 = fmaf(wv, v[kh + 2], a2);
        a3 = fmaf(wv, v[kh + 3], a3);
      }
    }
    int bi = h0 * 56 + wc;
    yp[bi]       = f2bf(a0 + bias + pl[(h0 + 3) * 64 + wc + 3]);
    yp[bi + 56]  = f2bf(a1 + bias + pl[(h0 + 4) * 64 + wc + 3]);
    yp[bi + 112] = f2bf(a2 + bias + pl[(h0 + 5) * 64 + wc + 3]);
    yp[bi + 168] = f2bf(a3 + bias + pl[(h0 + 6) * 64 + wc + 3]);
  }
}

// ---------------- MRConv4d: x_j = relu(max(4 rolled neighbors) - center), bf16 ----------------
__global__ void __launch_bounds__(256) xj_kernel(const __hip_bfloat16* __restrict__ y1,
                                                 __hip_bfloat16* __restrict__ xjb) {
  const int total = NB * HW * 24;               // 24 chunks of 8 channels
  const short* base = (const short*)y1;
  for (int idx = blockIdx.x * 256 + threadIdx.x; idx < total; idx += gridDim.x * 256) {
    int cg = idx % 24;
    int row = idx / 24;
    int b = row / HW, hw = row - b * HW;
    int h = hw / 56, wv = hw - h * 56;
    int hp = (h >= 54) ? h - 54 : h + 2;
    int hm = (h < 2) ? h + 54 : h - 2;
    int wpp = (wv >= 54) ? wv - 54 : wv + 2;
    int wmm = (wv < 2) ? wv + 54 : wv - 2;
    size_t rb = (size_t)b * HW;
    int co = cg * 8;
    short8 c0 = *(const short8*)(base + (rb + hw) * CC + co);
    short8 n1 = *(const short8*)(base + (rb + hp * 56 + wv) * CC + co);
    short8 n2 = *(const short8*)(base + (rb + hm * 56 + wv) * CC + co);
    short8 n3 = *(const short8*)(base + (rb + h * 56 + wpp) * CC + co);
    short8 n4 = *(const short8*)(base + (rb + h * 56 + wmm) * CC + co);
    short8 res;
#pragma unroll
    for (int j = 0; j < 8; ++j) {
      float m = fmaxf(fmaxf(bf2f(n1[j]), bf2f(n2[j])), fmaxf(bf2f(n3[j]), bf2f(n4[j])));
      m = fmaxf(m - bf2f(c0[j]), 0.0f);
      res[j] = f2bf(m);
    }
    *(short8*)((short*)xjb + (rb + hw) * CC + co) = res;
  }
}

// ---------------- unified MFMA GEMM over pixels ----------------
// MODE 0: gemm1  A=y0 (channel-major LDS, u16 gather), D[p][o] -> y1 bf16 [p][192]
// MODE 1: gemm2  A=[y1|xj] (two pixel-major bf16 sources), K=384, D[p][o], GELU -> y2 bf16
// MODE 2: gemm3  operands swapped: D[o][p] -> out FLOAT32 [b][o][hw] channel-major
template<int K_IN, int MODE>
__global__ void __launch_bounds__(256, 2) gemm_kernel(
    const __hip_bfloat16* __restrict__ act, const __hip_bfloat16* __restrict__ act2,
    const __hip_bfloat16* __restrict__ Wf, const float* __restrict__ bfv,
    void* __restrict__ outp) {
  extern __shared__ char smem[];
  const int t = threadIdx.x;
  const int lane = t & 63, w = t >> 6;
  const int bid = blockIdx.x;
  const int b = bid / 49, pt = bid - b * 49;
  const int p0 = pt * 64;

  // ---- stage 64-pixel tile into LDS (XOR bank-swizzled) ----
  if (MODE == 0) {
    // channel-major [192 c][64 px] bf16, row 128B; swizzle px ^= (((c>>3)&3)<<4)
    const __hip_bfloat16* src = act + (size_t)b * (CC * HW) + p0;
#pragma unroll
    for (int i = 0; i < 6; ++i) {
      int ch = i * 256 + t;
      int c = ch >> 3, pc = (ch & 7) * 8;
      int g = (c >> 3) & 3;
      short8 v = *(const short8*)((const short*)src + (size_t)c * HW + pc);
      *(short8*)(smem + c * 128 + ((pc ^ (g << 4)) * 2)) = v;
    }
  } else if (MODE == 1) {
    // pixel-major [64 px][384 k]: k<192 from act(y1), k>=192 from act2(xj); row 768B
#pragma unroll
    for (int i = 0; i < 12; ++i) {
      int ch = i * 256 + t;
      int p = ch / 48, q = ch - p * 48;
      const __hip_bfloat16* s = (q < 24) ? act : act2;
      int qq = (q < 24) ? q : q - 24;
      short8 v = *(const short8*)((const char*)s + (size_t)(b * HW + p0 + p) * 384 + qq * 16);
      *(short8*)(smem + p * 768 + ((q * 16) ^ ((p & 7) << 4))) = v;
    }
  } else {
    // pixel-major [64 px][192 k]; row 384B
#pragma unroll
    for (int i = 0; i < 6; ++i) {
      int ch = i * 256 + t;
      int p = ch / 24, q = ch - p * 24;
      short8 v = *(const short8*)((const char*)act + (size_t)(b * HW + p0 + p) * 384 + q * 16);
      *(short8*)(smem + p * 384 + ((q * 16) ^ ((p & 7) << 4))) = v;
    }
  }
  __syncthreads();

  // ---- compute: 4 waves = 2 px-halves x 2 o-halves; per wave 2x6 16x16 tiles ----
  const int wp = w & 1, wo = w >> 1;
  const int lrow = lane & 15, lhi = lane >> 4;
  f32x4 acc[2][6] = {};

#pragma unroll
  for (int kk = 0; kk < K_IN / 32; ++kk) {
    short8 af[2], wfr[6];
    if (MODE == 0) {
#pragma unroll
      for (int ai = 0; ai < 2; ++ai) {
        int p = wp * 32 + ai * 16 + lrow;
        int byte0 = (kk * 32 + lhi * 8) * 128 + ((p ^ (lhi << 4)) * 2);
#pragma unroll
        for (int j = 0; j < 8; ++j)
          af[ai][j] = *(const short*)(smem + byte0 + j * 128);
      }
    } else {
      const int rowB = K_IN * 2;
#pragma unroll
      for (int ai = 0; ai < 2; ++ai) {
        int p = wp * 32 + ai * 16 + lrow;
        int kbyte = kk * 64 + lhi * 16;
        af[ai] = *(const short8*)(smem + p * rowB + (kbyte ^ ((p & 7) << 4)));
      }
    }
#pragma unroll
    for (int wi = 0; wi < 6; ++wi) {
      int o = wo * 96 + wi * 16 + lrow;
      wfr[wi] = *(const short8*)((const short*)Wf + (size_t)o * K_IN + kk * 32 + lhi * 8);
    }
#pragma unroll
    for (int ai = 0; ai < 2; ++ai)
#pragma unroll
      for (int wi = 0; wi < 6; ++wi)
        acc[ai][wi] = (MODE == 2)
            ? __builtin_amdgcn_mfma_f32_16x16x32_bf16(wfr[wi], af[ai], acc[ai][wi], 0, 0, 0)
            : __builtin_amdgcn_mfma_f32_16x16x32_bf16(af[ai], wfr[wi], acc[ai][wi], 0, 0, 0);
  }

  // ---- epilogue ----
  if (MODE != 2) {
#pragma unroll
    for (int wi = 0; wi < 6; ++wi) {
      int o = wo * 96 + wi * 16 + lrow;
      float bias = bfv[o];
#pragma unroll
      for (int ai = 0; ai < 2; ++ai) {
#pragma unroll
        for (int r = 0; r < 4; ++r) {
          int p = wp * 32 + ai * 16 + lhi * 4 + r;
          float v = acc[ai][wi][r] + bias;
          if (MODE == 1) v = geluf(v);
          *((short*)outp + (size_t)(b * HW + p0 + p) * CC + o) = f2bf(v);
        }
      }
    }
  } else {
#pragma unroll
    for (int wi = 0; wi < 6; ++wi) {
#pragma unroll
      for (int r = 0; r < 4; ++r) {
        int o = wo * 96 + wi * 16 + lhi * 4 + r;
        float bias = bfv[o];
#pragma unroll
        for (int ai = 0; ai < 2; ++ai) {
          int p = wp * 32 + ai * 16 + lrow;
          float v = acc[ai][wi][r] + bias;
          *((float*)outp + ((size_t)b * CC + o) * HW + p0 + p) = v;
        }
      }
    }
  }
}

extern "C" void kernel_launch(void* const* d_in, const int* in_sizes, int n_in,
                              void* d_out, int out_size, void* d_ws, size_t ws_size,
                              hipStream_t stream) {
  const float* x     = (const float*)d_in[0];
  const float* cpe_w = (const float*)d_in[1];
  const float* cpe_b = (const float*)d_in[2];
  const float* fc1_w = (const float*)d_in[3];
  const float* fc1_b = (const float*)d_in[4];
  const float* bn1_g = (const float*)d_in[5];
  const float* bn1_b = (const float*)d_in[6];
  const float* bn1_m = (const float*)d_in[7];
  const float* bn1_v = (const float*)d_in[8];
  const float* gc_w  = (const float*)d_in[9];
  const float* gc_b  = (const float*)d_in[10];
  const float* bng_g = (const float*)d_in[11];
  const float* bng_b = (const float*)d_in[12];
  const float* bng_m = (const float*)d_in[13];
  const float* bng_v = (const float*)d_in[14];
  const float* fc2_w = (const float*)d_in[15];
  const float* fc2_b = (const float*)d_in[16];
  const float* bn2_g = (const float*)d_in[17];
  const float* bn2_b = (const float*)d_in[18];
  const float* bn2_m = (const float*)d_in[19];
  const float* bn2_v = (const float*)d_in[20];

  // workspace layout (bytes)
  //   0        W1f  73728
  //   73728    Wgf  147456
  //   221184   W2f  73728
  //   294912   b1f  768 | 295680 bgf 768 | 296448 b2f 768
  //   524288   y0 / y2   38535168  (bf16)
  //   39059456 xjb       38535168  (bf16)     total 77594624
  if (ws_size < 77594624) return;
  char* ws = (char*)d_ws;
  __hip_bfloat16* W1f = (__hip_bfloat16*)(ws);
  __hip_bfloat16* Wgf = (__hip_bfloat16*)(ws + 73728);
  __hip_bfloat16* W2f = (__hip_bfloat16*)(ws + 221184);
  float* b1f = (float*)(ws + 294912);
  float* bgf = (float*)(ws + 295680);
  float* b2f = (float*)(ws + 296448);
  __hip_bfloat16* y0  = (__hip_bfloat16*)(ws + 524288);       // later reused as y2
  __hip_bfloat16* xjb = (__hip_bfloat16*)(ws + 39059456);
  __hip_bfloat16* y1  = (__hip_bfloat16*)d_out;               // d_out (77MB f32) as bf16 scratch
  float* out = (float*)d_out;

  fold_kernel<<<576, 256, 0, stream>>>(fc1_w, fc1_b, bn1_g, bn1_b, bn1_m, bn1_v,
      gc_w, gc_b, bng_g, bng_b, bng_m, bng_v, fc2_w, fc2_b, bn2_g, bn2_b, bn2_m, bn2_v,
      W1f, Wgf, W2f, b1f, bgf, b2f);
  dwconv_kernel<<<NB * CC, 256, 0, stream>>>(x, cpe_w, cpe_b, y0);
  gemm_kernel<192, 0><<<NB * 49, 256, 24576, stream>>>(y0, nullptr, W1f, b1f, y1);
  xj_kernel<<<2048, 256, 0, stream>>>(y1, xjb);
  gemm_kernel<384, 1><<<NB * 49, 256, 49152, stream>>>(y1, xjb, Wgf, bgf, y0);
  gemm_kernel<192, 2><<<NB * 49, 256, 24576, stream>>>(y0, nullptr, W2f, b2f, out);
}